// Round 6
// baseline (648.308 us; speedup 1.0000x reference)
//
#include <hip/hip_runtime.h>
#include <math.h>

#define D_DIM 2048
#define T_DIM 128
#define TT 16

typedef __attribute__((address_space(1))) const unsigned int gu32;
typedef __attribute__((address_space(3))) unsigned int su32;

// One-shot T-space row swizzles (2048 rows x 16 words).  Bank bit4 = row&1.
// T1: flip row-bit0 by e-bit5. write e=(j<<5)|r: e5=j0 const, row0=r0^j0 -> 2-way.
//     read  e=(j&31)|(j5<<10)|(r<<5): e5=r0, row0=j0^r0 -> 2-way.
__device__ __forceinline__ int rw1(int e) { return e ^ ((e >> 5) & 1); }
// T2: flip row-bit0 by e-bit5 ^ e-bit1. write (P2-order): e5=r0, e1=j1 const -> 2-way.
//     read (P3-order): e5=j1 const, e1=r0 -> 2-way.
__device__ __forceinline__ int rw2(int e) { return e ^ ((e >> 5) & 1) ^ ((e >> 1) & 1); }
// T3 (R5-proven 2-round map on e''=e>>1), relocated to rows 1024..2047
__device__ __forceinline__ int sw2(int x) { return x ^ ((x >> 4) & 1); }

// radix-2 butterfly over register-index bit MM (fully unrolled, constant idx)
#define BFLY(MM)                                              \
    _Pragma("unroll")                                         \
    for (int i_ = 0; i_ < 64; ++i_) {                         \
        if ((i_ & (MM)) == 0) {                               \
            float a_ = v[i_], b_ = v[i_ | (MM)];              \
            v[i_] = a_ + b_;                                  \
            v[i_ | (MM)] = a_ - b_;                           \
        }                                                     \
    }

// LDS-only barrier: drains lgkmcnt, NOT vmcnt -> gl_lds prefetch stays in
// flight across it (m201 pattern).
__device__ __forceinline__ void barx() {
    asm volatile("s_waitcnt lgkmcnt(0)" ::: "memory");
    __builtin_amdgcn_s_barrier();
    asm volatile("" ::: "memory");
}
#define VWAIT(N) asm volatile("s_waitcnt vmcnt(" #N ")" ::: "memory")

// Empirical (R2/R3/R5): VGPR cap = 256/arg; occupancy = floor(256/VGPR) waves
// per SIMD.  arg=2 -> cap 128, no spill for v[64]+temps; LDS 160 KiB pins
// 1 block/CU = 2 waves/SIMD regardless (structural this round).
__global__ __launch_bounds__(512, 2)
void fwht_apply_kernel(const float* __restrict__ z,
                       const float* __restrict__ d1,
                       const float* __restrict__ d2,
                       const float* __restrict__ d3,
                       const float* __restrict__ bvec,
                       const float* __restrict__ sldj_in,
                       float* __restrict__ out) {
    extern __shared__ float sh[];
    // words 0..32767: staged tile [e][16t] (e10 selects 64KiB half); reused
    // as one-shot T-space (T1/T2: rows 0..2047, T3: rows 1024..2047).
    float* d1l = sh + 32768;        // d tables, pre-scaled by s (8 KiB each)
    float* d2l = sh + 34816;
    float* d3l = sh + 36864;
    float* bl  = sh + 38912;        // total 40960 floats = 160 KiB
    const int tid = threadIdx.x;

    if (blockIdx.x == 256) {        // ---- sldj block ----
        float acc = 0.0f;
        for (int i = tid; i < D_DIM; i += 512)
            acc += logf(fabsf(d1[i])) + logf(fabsf(d2[i])) + logf(fabsf(d3[i]));
        sh[tid] = acc;
        __syncthreads();
        #pragma unroll
        for (int sft = 256; sft > 0; sft >>= 1) {
            if (tid < sft) sh[tid] += sh[tid + sft];
            __syncthreads();
        }
        if (tid < 128)
            out[(size_t)4 * 32 * 2048 * 128 + tid] = sldj_in[tid] + sh[0];
        return;
    }

    const int r    = tid >> 4;      // 5-bit "rest" coordinate (0..31)
    const int tt   = tid & 15;      // t within tile (0..15)
    const int b    = blockIdx.x;    // block owns taus 4b..4b+3 (same km-slab
    const int wid  = tid >> 6;      //  pairing of 64B line-halves as R5)
    const int lane = tid & 63;
    const int q    = lane >> 2;     // row-within-run (0..15)
    const int c    = lane & 3;      // float4 slot within 64B row
    const float s  = 0.022097086912079608f;   // 1/sqrt(2048)

    for (int k = tid; k < D_DIM; k += 512) {
        d1l[k] = d1[k] * s;
        d2l[k] = d2[k] * s;
        d3l[k] = d3[k] * s;
        bl[k]  = bvec[k];
    }

    // Stage one 64KiB half (h = e-bit10 = j5): 8 gl_lds/wave, 16 rows x 64B
    // each.  LDS dest word = e*16 + 4c (linear in lane order, m104-safe).
    auto issue = [&](int tau, int h) {
        const float* zs = z + ((size_t)(tau >> 3) << 18) + ((tau & 7) << 4) + (c << 2);
        float* buf = sh + (h << 14);
        #pragma unroll
        for (int i = 0; i < 8; ++i) {
            const int n = (wid << 3) | i;               // run 0..63
            const int e = (h << 10) | (n << 4) | q;
            __builtin_amdgcn_global_load_lds((gu32*)(zs + (size_t)e * T_DIM),
                                             (su32*)(buf + (n << 8)), 16, 0, 0);
        }
    };

    issue(b << 2, 0);
    issue(b << 2, 1);
    VWAIT(0);
    barx();                          // tables + first tile staged

    #pragma unroll 1
    for (int ti = 0; ti < 4; ++ti) {
        const int tau = (b << 2) | ti;
        const int eR  = ((r & 15) << 1) | ((r >> 4) << 10);
        float v[64];

        VWAIT(16);                   // both halves landed (no-op on ti=0);
        barx();                      // drains prior stores en route (in-order)

        // ---- merged full-width staged read: bank = (r0<<4)|tt -> 2-way ----
        #pragma unroll
        for (int j = 0; j < 64; ++j) {
            const int e = (j << 5) | r;
            v[j] = sh[(e << 4) + tt] * d1l[e];  // d1l: 4-addr broadcast, free
        }
        // ---- P1: e = (j<<5)|r.  F1 on e-bits 5..10 ----
        BFLY(1) BFLY(2) BFLY(4) BFLY(8) BFLY(16) BFLY(32)
        barx();                      // all staged reads done -> T-space writable

        // ---- T1 one-shot (P1 -> P2 relabel over full 2048-row space) ----
        #pragma unroll
        for (int j = 0; j < 64; ++j)
            sh[(rw1((j << 5) | r) << 4) + tt] = v[j];
        barx();
        #pragma unroll
        for (int j = 0; j < 64; ++j)
            v[j] = sh[(rw1((j & 31) | ((j >> 5) << 10) | (r << 5)) << 4) + tt];
        barx();

        // ---- P2: e = (j&31) | (j5<<10) | (r<<5) ----
        BFLY(1) BFLY(2) BFLY(4) BFLY(8) BFLY(16)          // F1 done
        {   // * d2 (pre-scaled): two contiguous runs of 32 -> float4
            const float4* q0 = (const float4*)(d2l + (r << 5));
            const float4* q1 = (const float4*)(d2l + 1024 + (r << 5));
            #pragma unroll
            for (int qq = 0; qq < 8; ++qq) {
                float4 a = q0[qq];
                v[4*qq+0] *= a.x; v[4*qq+1] *= a.y;
                v[4*qq+2] *= a.z; v[4*qq+3] *= a.w;
                float4 cc = q1[qq];
                v[32+4*qq+0] *= cc.x; v[32+4*qq+1] *= cc.y;
                v[32+4*qq+2] *= cc.z; v[32+4*qq+3] *= cc.w;
            }
        }
        BFLY(1) BFLY(2) BFLY(4) BFLY(8) BFLY(16) BFLY(32) // F2 e-bits 0..4,10

        // ---- T2 one-shot (P2 -> P3 relabel) ----
        #pragma unroll
        for (int j = 0; j < 64; ++j)
            sh[(rw2((j & 31) | ((j >> 5) << 10) | (r << 5)) << 4) + tt] = v[j];
        barx();
        #pragma unroll
        for (int j = 0; j < 64; ++j)
            v[j] = sh[(rw2(((j >> 1) << 5) | (j & 1) | eR) << 4) + tt];
        barx();

        if (ti < 3) issue(tau + 1, 0);   // rows 0..1023 free from here on

        // ---- P3: e = ((j>>1)<<5)|(j&1)|eR ----
        BFLY(2) BFLY(4) BFLY(8) BFLY(16) BFLY(32)         // F2 done
        {   // * d3 (pre-scaled): (v[2m], v[2m+1]) at (e, e+1) -> float2
            #pragma unroll
            for (int m = 0; m < 32; ++m) {
                float2 a = *(const float2*)(d3l + ((m << 5) | eR));
                v[2*m]   *= a.x;
                v[2*m+1] *= a.y;
            }
        }
        BFLY(2) BFLY(4) BFLY(8) BFLY(16) BFLY(32) BFLY(1) // F3 e-bits 5..9, 0

        // ---- T3: R5-proven 2-round map on e>>1, rows 1024..2047 ----
        #pragma unroll
        for (int h2 = 0; h2 < 2; ++h2) {
            #pragma unroll
            for (int j = h2; j < 64; j += 2)
                sh[((1024 + sw2(((j >> 1) << 4) | (r & 15) | ((r >> 4) << 9))) << 4) + tt] = v[j];
            barx();
            #pragma unroll
            for (int j = h2; j < 64; j += 2)
                v[j] = sh[((1024 + sw2(((j >> 1) & 15) | (r << 4) | ((j >> 5) << 9))) << 4) + tt];
            barx();
        }

        if (ti < 3) issue(tau + 1, 1);   // rows 1024..2047 free after T3

        // ---- P4: e = (j&31) | (j5<<10) | (r<<5). F3 e-bits 1..4, 10 ----
        BFLY(2) BFLY(4) BFLY(8) BFLY(16) BFLY(32)         // F3 done

        float* ob = out + ((size_t)(tau >> 3) << 18) + ((tau & 7) << 4) + tt;
        {   // + b, store (R0-proven map: 4 x 64B fully-used segments/instr)
            const float4* q0 = (const float4*)(bl + (r << 5));
            const float4* q1 = (const float4*)(bl + 1024 + (r << 5));
            #pragma unroll
            for (int qq = 0; qq < 8; ++qq) {
                float4 a = q0[qq];
                const int e0 = (r << 5) + 4*qq;
                ob[(size_t)(e0+0) * T_DIM] = v[4*qq+0] + a.x;
                ob[(size_t)(e0+1) * T_DIM] = v[4*qq+1] + a.y;
                ob[(size_t)(e0+2) * T_DIM] = v[4*qq+2] + a.z;
                ob[(size_t)(e0+3) * T_DIM] = v[4*qq+3] + a.w;
                float4 cc = q1[qq];
                const int e1 = 1024 + (r << 5) + 4*qq;
                ob[(size_t)(e1+0) * T_DIM] = v[32+4*qq+0] + cc.x;
                ob[(size_t)(e1+1) * T_DIM] = v[32+4*qq+1] + cc.y;
                ob[(size_t)(e1+2) * T_DIM] = v[32+4*qq+2] + cc.z;
                ob[(size_t)(e1+3) * T_DIM] = v[32+4*qq+3] + cc.w;
            }
        }
    }
}

extern "C" void kernel_launch(void* const* d_in, const int* in_sizes, int n_in,
                              void* d_out, int out_size, void* d_ws, size_t ws_size,
                              hipStream_t stream) {
    const float* z    = (const float*)d_in[0];
    const float* d1   = (const float*)d_in[1];
    const float* d2   = (const float*)d_in[2];
    const float* d3   = (const float*)d_in[3];
    const float* bvec = (const float*)d_in[4];
    const float* sldj = (const float*)d_in[5];
    float* out = (float*)d_out;

    static bool attr_set = false;
    if (!attr_set) {
        hipFuncSetAttribute((const void*)fwht_apply_kernel,
                            hipFuncAttributeMaxDynamicSharedMemorySize, 163840);
        attr_set = true;
    }

    // blocks 0..255: one per CU, 4 t-tiles of one km-slab each, deep-
    // prefetched single-block pipeline; block 256: sldj
    fwht_apply_kernel<<<257, 512, 163840, stream>>>(z, d1, d2, d3, bvec, sldj, out);
}

// Round 7
// 309.306 us; speedup vs baseline: 2.0960x; 2.0960x over previous
//
#include <hip/hip_runtime.h>
#include <math.h>

#define T_DIM 128

typedef __attribute__((address_space(1))) const unsigned int gu32;
typedef __attribute__((address_space(3))) unsigned int su32;

// butterfly over register-index bit MM, index subrange [LO, LO+CNT)
#define BFLY_R(MM, LO, CNT)                                   \
    _Pragma("unroll")                                         \
    for (int i_ = (LO); i_ < (LO) + (CNT); ++i_) {            \
        if ((i_ & (MM)) == 0) {                               \
            float a_ = v[i_], b_ = v[i_ | (MM)];              \
            v[i_] = a_ + b_;                                  \
            v[i_ | (MM)] = a_ - b_;                           \
        }                                                     \
    }
#define BFLY(MM) BFLY_R(MM, 0, 64)

// LDS-only barrier: drains lgkmcnt, NOT vmcnt -> gl_lds prefetch stays in
// flight across it.
__device__ __forceinline__ void barx() {
    asm volatile("s_waitcnt lgkmcnt(0)" ::: "memory");
    __builtin_amdgcn_s_barrier();
    asm volatile("" ::: "memory");
}
#define VWAIT(N) asm volatile("s_waitcnt vmcnt(" #N ")" ::: "memory")

// 1024-thread block: 16 waves = 4 waves/SIMD forced by block size (2x R5
// residency).  HW schedulability then caps VGPR at 512/4 = 128; essential
// pressure ~90 -> headroom (R6 lesson: sitting AT the cap risks spill).
__global__ __launch_bounds__(1024, 1)
void fwht_apply_kernel(const float* __restrict__ z,
                       const float* __restrict__ d1,
                       const float* __restrict__ d2,
                       const float* __restrict__ d3,
                       const float* __restrict__ bvec,
                       const float* __restrict__ sldj_in,
                       float* __restrict__ out) {
    extern __shared__ float sh[];
    // words 0..32767: stage ring (buf0 = 0..16383, buf1 = 16384..32767),
    // reused whole as T-space (1024 rows x 32 t-words).  No swizzle needed:
    // every access pattern is 2 rows x 32 tt per instruction -> 2-way (free).
    float* d1l = sh + 32768;        // tables, d1/d2/d3 pre-scaled by s
    float* d2l = sh + 34816;
    float* d3l = sh + 36864;
    float* bl  = sh + 38912;        // total 40960 floats = 160 KiB exactly
    const int tid = threadIdx.x;

    if (blockIdx.x == 256) {        // ---- sldj block ----
        float acc = 0.0f;
        for (int i = tid; i < 2048; i += 1024)
            acc += logf(fabsf(d1[i])) + logf(fabsf(d2[i])) + logf(fabsf(d3[i]));
        sh[tid] = acc;
        __syncthreads();
        #pragma unroll
        for (int sft = 512; sft > 0; sft >>= 1) {
            if (tid < sft) sh[tid] += sh[tid + sft];
            __syncthreads();
        }
        if (tid < 128)
            out[(size_t)4 * 32 * 2048 * 128 + tid] = sldj_in[tid] + sh[0];
        return;
    }

    const int r    = tid >> 5;      // 5-bit "rest" coordinate (0..31)
    const int tt   = tid & 31;      // t within 32-wide quad (0..31)
    const int b    = blockIdx.x;    // tiles tau = 2b, 2b+1; km = b>>1
    const int km   = b >> 1;
    const int wv   = tid >> 6;      // wave id (0..15)
    const int lane = tid & 63;
    const float s  = 0.022097086912079608f;   // 1/sqrt(2048)

    for (int k = tid; k < 2048; k += 1024) {
        d1l[k] = d1[k] * s;
        d2l[k] = d2[k] * s;
        d3l[k] = d3[k] * s;
        bl[k]  = bvec[k];
    }

    const float* zkm = z + ((size_t)km << 18) + ((lane & 7) << 2);

    // Stage round q (j-quad q: j in [16q,16q+16), e = (q<<9)|row, row<512):
    // 4 gl_lds/wave, each 8 rows x 128B CONTIGUOUS ALIGNED FULL LINES.
    // LDS dest word = bufbase + g*256 + lane*4 (linear, m104-safe); holds
    // [row][t-t0] at word row*32 + (t-t0).
    auto issue = [&](int ti, int q) {
        const float* zs = zkm + ((((b & 1) << 1) | ti) << 5);
        float* buf = sh + ((q & 1) << 14);
        #pragma unroll
        for (int i = 0; i < 4; ++i) {
            const int g = (wv << 2) | i;                // row-group 0..63
            const int e = (q << 9) | (g << 3) | (lane >> 3);
            __builtin_amdgcn_global_load_lds((gu32*)(zs + (size_t)e * T_DIM),
                                             (su32*)(buf + (g << 8)), 16, 0, 0);
        }
    };

    issue(0, 0);
    issue(0, 1);
    VWAIT(0);
    barx();                          // tables + q0,q1 of tile 0 resident

    #pragma unroll 1
    for (int ti = 0; ti < 2; ++ti) {
        float v[64];

        VWAIT(63);                   // in-order: <=63 outstanding ==> the 9+
        barx();                      // oldest (q0,q1 gl_lds) retired. ti=0: no-op.

        // ---- staged reads: 4 full-width j-quad rounds, ring buf0/buf1.
        // bank = tt -> 2 rows/instr = 2-way, free.  d1 folded at load.
        #pragma unroll
        for (int jj = 0; jj < 16; ++jj) {               // q0 -> v[0..15]
            const int row = (jj << 5) | r;
            v[jj] = sh[(row << 5) + tt] * d1l[row];     // e = row for q0
        }
        BFLY_R(1,0,16) BFLY_R(2,0,16) BFLY_R(4,0,16) BFLY_R(8,0,16)
        barx();                      // buf0 readers done
        issue(ti, 2);
        #pragma unroll
        for (int jj = 0; jj < 16; ++jj) {               // q1 -> v[16..31]
            const int row = (jj << 5) | r;
            v[16 + jj] = sh[16384 + (row << 5) + tt] * d1l[512 + row];
        }
        BFLY_R(1,16,16) BFLY_R(2,16,16) BFLY_R(4,16,16) BFLY_R(8,16,16)
        BFLY_R(16,0,32)
        barx();                      // buf1 readers done
        issue(ti, 3);
        VWAIT(4);                    // q2 landed (only q3 newer)
        barx();
        #pragma unroll
        for (int jj = 0; jj < 16; ++jj) {               // q2 -> v[32..47]
            const int row = (jj << 5) | r;
            v[32 + jj] = sh[(row << 5) + tt] * d1l[1024 + row];
        }
        BFLY_R(1,32,16) BFLY_R(2,32,16) BFLY_R(4,32,16) BFLY_R(8,32,16)
        VWAIT(0);                    // q3 landed
        barx();
        #pragma unroll
        for (int jj = 0; jj < 16; ++jj) {               // q3 -> v[48..63]
            const int row = (jj << 5) | r;
            v[48 + jj] = sh[16384 + (row << 5) + tt] * d1l[1536 + row];
        }
        BFLY_R(1,48,16) BFLY_R(2,48,16) BFLY_R(4,48,16) BFLY_R(8,48,16)
        BFLY_R(16,32,32) BFLY(32)    // F1 on e-bits 5..10 complete (P1 done)
        barx();                      // staged reads done -> T-space writable

        // ---- T1 (P1->P2): 2 rounds on e10 = j5.  1024 rows x 32. ----
        #pragma unroll
        for (int h = 0; h < 2; ++h) {
            #pragma unroll
            for (int jj = 0; jj < 32; ++jj)             // write: row=(j&31)<<5|r
                sh[((((jj << 5) | r)) << 5) + tt] = v[(h << 5) | jj];
            barx();
            #pragma unroll
            for (int jj = 0; jj < 32; ++jj)             // read (P2): row=(j&31)|(r<<5)
                v[(h << 5) | jj] = sh[(((jj) | (r << 5)) << 5) + tt];
            barx();
        }

        // ---- P2: e = (j&31) | (j5<<10) | (r<<5) ----
        BFLY(1) BFLY(2) BFLY(4) BFLY(8) BFLY(16)          // F1 done
        {   // * d2 (pre-scaled): two contiguous runs of 32 -> float4
            const float4* q0 = (const float4*)(d2l + (r << 5));
            const float4* q1 = (const float4*)(d2l + 1024 + (r << 5));
            #pragma unroll
            for (int qq = 0; qq < 8; ++qq) {
                float4 a = q0[qq];
                v[4*qq+0] *= a.x; v[4*qq+1] *= a.y;
                v[4*qq+2] *= a.z; v[4*qq+3] *= a.w;
                float4 cc = q1[qq];
                v[32+4*qq+0] *= cc.x; v[32+4*qq+1] *= cc.y;
                v[32+4*qq+2] *= cc.z; v[32+4*qq+3] *= cc.w;
            }
        }
        BFLY(1) BFLY(2) BFLY(4) BFLY(8) BFLY(16) BFLY(32) // F2 e-bits 0..4,10

        // ---- T2 (P2->P3): 2 rounds on e0 = j0; rows = e>>1 ----
        #pragma unroll
        for (int h2 = 0; h2 < 2; ++h2) {
            #pragma unroll
            for (int mm = 0; mm < 32; ++mm) {           // write: P2-order
                const int row = (mm & 15) | ((mm >> 4) << 9) | (r << 4);
                sh[(row << 5) + tt] = v[(mm << 1) | h2];
            }
            barx();
            #pragma unroll
            for (int mm = 0; mm < 32; ++mm) {           // read: P3-order
                const int row = (mm << 4) | (r & 15) | ((r >> 4) << 9);
                v[(mm << 1) | h2] = sh[(row << 5) + tt];
            }
            barx();
        }

        // ---- P3: e = ((j>>1)<<5)|(j&1)|eR, eR = ((r&15)<<1)|((r>>4)<<10)
        BFLY(2) BFLY(4) BFLY(8) BFLY(16) BFLY(32)         // F2 done
        {   // * d3 (pre-scaled): (v[2m], v[2m+1]) at (e, e+1) -> float2
            const int eR = ((r & 15) << 1) | ((r >> 4) << 10);
            #pragma unroll
            for (int m = 0; m < 32; ++m) {
                float2 a = *(const float2*)(d3l + ((m << 5) | eR));
                v[2*m]   *= a.x;
                v[2*m+1] *= a.y;
            }
        }
        BFLY(2) BFLY(4) BFLY(8) BFLY(16) BFLY(32) BFLY(1) // F3 e-bits 5..9, 0

        // ---- T3 (P3->P4): 2 rounds on e0 = j0 (mirror of T2) ----
        #pragma unroll
        for (int h2 = 0; h2 < 2; ++h2) {
            #pragma unroll
            for (int mm = 0; mm < 32; ++mm) {           // write: P3-order
                const int row = (mm << 4) | (r & 15) | ((r >> 4) << 9);
                sh[(row << 5) + tt] = v[(mm << 1) | h2];
            }
            barx();
            #pragma unroll
            for (int mm = 0; mm < 32; ++mm) {           // read: P4(=P2)-order
                const int row = (mm & 15) | ((mm >> 4) << 9) | (r << 4);
                v[(mm << 1) | h2] = sh[(row << 5) + tt];
            }
            barx();
        }

        if (ti == 0) { issue(1, 0); issue(1, 1); }  // next tile; lands under
                                                    // P4 + stores
        // ---- P4: e = (j&31)|(j5<<10)|(r<<5).  F3 e-bits 1..4, 10 ----
        BFLY(2) BFLY(4) BFLY(8) BFLY(16) BFLY(32)         // F3 done

        const int t0 = (((b & 1) << 1) | ti) << 5;
        float* ob = out + ((size_t)km << 18) + t0 + tt;
        {   // + b, store: per instruction 2 x 128B aligned full segments
            const float4* q0 = (const float4*)(bl + (r << 5));
            const float4* q1 = (const float4*)(bl + 1024 + (r << 5));
            #pragma unroll
            for (int qq = 0; qq < 8; ++qq) {
                float4 a = q0[qq];
                const int e0 = (r << 5) + 4*qq;
                ob[(size_t)(e0+0) * T_DIM] = v[4*qq+0] + a.x;
                ob[(size_t)(e0+1) * T_DIM] = v[4*qq+1] + a.y;
                ob[(size_t)(e0+2) * T_DIM] = v[4*qq+2] + a.z;
                ob[(size_t)(e0+3) * T_DIM] = v[4*qq+3] + a.w;
                float4 cc = q1[qq];
                const int e1 = 1024 + (r << 5) + 4*qq;
                ob[(size_t)(e1+0) * T_DIM] = v[32+4*qq+0] + cc.x;
                ob[(size_t)(e1+1) * T_DIM] = v[32+4*qq+1] + cc.y;
                ob[(size_t)(e1+2) * T_DIM] = v[32+4*qq+2] + cc.z;
                ob[(size_t)(e1+3) * T_DIM] = v[32+4*qq+3] + cc.w;
            }
        }
    }
}

extern "C" void kernel_launch(void* const* d_in, const int* in_sizes, int n_in,
                              void* d_out, int out_size, void* d_ws, size_t ws_size,
                              hipStream_t stream) {
    const float* z    = (const float*)d_in[0];
    const float* d1   = (const float*)d_in[1];
    const float* d2   = (const float*)d_in[2];
    const float* d3   = (const float*)d_in[3];
    const float* bvec = (const float*)d_in[4];
    const float* sldj = (const float*)d_in[5];
    float* out = (float*)d_out;

    static bool attr_set = false;
    if (!attr_set) {
        hipFuncSetAttribute((const void*)fwht_apply_kernel,
                            hipFuncAttributeMaxDynamicSharedMemorySize, 163840);
        attr_set = true;
    }

    // blocks 0..255: one per CU, two 32-wide t-quads of one km-slab each
    // (all HBM transactions full 128B lines); block 256: sldj
    fwht_apply_kernel<<<257, 1024, 163840, stream>>>(z, d1, d2, d3, bvec, sldj, out);
}